// Round 15
// baseline (93.449 us; speedup 1.0000x reference)
//
#include <hip/hip_runtime.h>

// Problem constants (match reference): B=64, L=2048, H=256, K=32
#define LL 2048
#define BB 64
#define HH 256
#define KK 32

#define NB  768    // 3 blocks/CU (LDS-limited: ~49.5 KB/block)
#define WPB 4      // waves per block

typedef __attribute__((ext_vector_type(8))) short  short8;   // 8 bf16 (4 VGPRs)
typedef __attribute__((ext_vector_type(4))) float  f32x4;

__device__ __forceinline__ float softplus_f(float x) {
    return x > 20.f ? x : __logf(1.f + __expf(x));
}
// round-to-nearest-even fp32 -> bf16
__device__ __forceinline__ unsigned f2bf(float x) {
    unsigned u = __builtin_bit_cast(unsigned, x);
    return (u + 0x7FFFu + ((u >> 16) & 1u)) >> 16;
}

struct RowT { float4 h, c, t, o, d; };

__device__ __forceinline__ RowT load_row(
    const float* __restrict__ hidden, const float* __restrict__ cell,
    const float* __restrict__ ctarg,  const float* __restrict__ outp,
    const float* __restrict__ decay,  int r, int lane)
{
    const int base = r * HH + lane * 4;
    RowT x;
    x.h = *(const float4*)(hidden + base);
    x.c = *(const float4*)(cell   + base);
    x.t = *(const float4*)(ctarg  + base);
    x.o = *(const float4*)(outp   + base);
    x.d = *(const float4*)(decay  + base);
    return x;
}

// Row J: compute v = o*tanh(c_sim), write v (row J) and h (row 8+J) bf16x4
// to the swizzled per-wave A-tile.
template<int J>
__device__ __forceinline__ void STrow(char* Aw, const RowT& R, float stv, int lane)
{
    float4 v;
    float cs, e2;
    cs = R.t.x + (R.c.x - R.t.x) * __expf(-R.d.x * stv); e2 = __expf(2.f * cs); v.x = R.o.x * ((e2 - 1.f) / (e2 + 1.f));
    cs = R.t.y + (R.c.y - R.t.y) * __expf(-R.d.y * stv); e2 = __expf(2.f * cs); v.y = R.o.y * ((e2 - 1.f) / (e2 + 1.f));
    cs = R.t.z + (R.c.z - R.t.z) * __expf(-R.d.z * stv); e2 = __expf(2.f * cs); v.z = R.o.z * ((e2 - 1.f) / (e2 + 1.f));
    cs = R.t.w + (R.c.w - R.t.w) * __expf(-R.d.w * stv); e2 = __expf(2.f * cs); v.w = R.o.w * ((e2 - 1.f) / (e2 + 1.f));
    const int swz = (J & 7) << 4;      // (8+J)&7 == J&7
    *(uint2*)(Aw + ((J * 512 + lane * 8) ^ swz)) =
        make_uint2(f2bf(v.x) | (f2bf(v.y) << 16), f2bf(v.z) | (f2bf(v.w) << 16));
    *(uint2*)(Aw + (((8 + J) * 512 + lane * 8) ^ swz)) =
        make_uint2(f2bf(R.h.x) | (f2bf(R.h.y) << 16), f2bf(R.h.z) | (f2bf(R.h.w) << 16));
}

// R9 structure + cross-tile 2-row prefetch: during tile t's MFMA/epilogue,
// tile t+1's metadata and first two row-loads are already in flight.
__global__ __launch_bounds__(256, 3) void nhll_main(
    const int*   __restrict__ events,   // [B, L]
    const int*   __restrict__ lens,     // [B]
    const float* __restrict__ ttime,    // [B]
    const float* __restrict__ hidden,   // [L, B, H]
    const float* __restrict__ cell,     // [L, B, H]
    const float* __restrict__ ctarg,    // [L, B, H]
    const float* __restrict__ outp,     // [L, B, H]
    const float* __restrict__ decay,    // [L, B, H]
    const float* __restrict__ simt,     // [L, B]
    const float* __restrict__ W,        // [H, K]
    const float* __restrict__ bias,     // [K]
    float*       __restrict__ partial)  // [NB]
{
    __shared__ __align__(16) char  WTs[KK * HH * 2];        // 16 KB W^T bf16, swizzled
    __shared__ __align__(16) char  Als[WPB][16 * HH * 2];   // 8 KB per wave
    __shared__ int   pfx[BB + 1];
    __shared__ float coef_s[BB];
    __shared__ float bias_s[KK];
    __shared__ float wacc[WPB];

    const int tid  = threadIdx.x;
    const int lane = tid & 63;
    const int q    = tid >> 6;
    const int g    = lane >> 4;     // h-octet within K-chunk
    const int m    = lane & 15;     // A-row / C-col index

    // ---- one-time: W^T bf16 into LDS (row k, position h=tid, swizzled) ----
    {
        const float* wrow = &W[tid * KK];
#pragma unroll
        for (int k = 0; k < KK; ++k) {
            const int byte = (k * 512 + tid * 2) ^ ((k & 7) << 4);
            *(unsigned short*)(WTs + byte) = (unsigned short)f2bf(wrow[k]);
        }
    }
    if (tid < KK) bias_s[tid] = bias[tid];
    if (tid < BB) {                 // wave 0: scan lens -> prefix sums
        const int ln = lens[tid];
        coef_s[tid] = ttime[tid] / (float)ln;
        int s = ln;
#pragma unroll
        for (int mm = 1; mm < 64; mm <<= 1) {
            const int t = __shfl_up(s, mm, 64);
            if (lane >= mm) s += t;
        }
        pfx[tid + 1] = s;
        if (tid == 0) pfx[0] = 0;
    }
    __syncthreads();

    const float b_lo = bias_s[m];
    const float b_hi = bias_s[16 + m];
    const int   T      = pfx[BB];
    const int   ntiles = (T + 7) >> 3;
    const int   stride = NB * WPB;
    char* Aw = Als[q];
    float acc = 0.f;

    // per-lane metadata for a tile: lane j (j = lane&7) owns flat row tile*8+j
#define META(TILE, R_, ST_, E_, CF_, V_) do {                                 \
        int i_ = (TILE) * 8 + (lane & 7);                                     \
        V_ = (i_ < T) ? 1 : 0;                                                \
        if (!V_) i_ = T - 1;                                                  \
        int lo_ = 0, hi_ = BB;                                                \
        _Pragma("unroll")                                                     \
        for (int s_ = 0; s_ < 6; ++s_) {                                      \
            const int mid_ = (lo_ + hi_) >> 1;                                \
            if (pfx[mid_] <= i_) lo_ = mid_; else hi_ = mid_;                 \
        }                                                                     \
        const int b_ = lo_;                                                   \
        const int l_ = i_ - pfx[b_];                                          \
        R_  = l_ * BB + b_;                                                   \
        ST_ = simt[R_];                                                       \
        CF_ = V_ ? coef_s[b_] : 0.f;                                          \
        E_  = events[b_ * LL + l_ + 1];   /* l+1 <= len <= 2046 */            \
    } while (0)

    int tile = blockIdx.x * WPB + q;
    if (tile < ntiles) {
        int r, e, valid; float st, coef;
        META(tile, r, st, e, coef, valid);
        float ss0 = __shfl(st, 0, 64), ss1 = __shfl(st, 1, 64);
        RowT b0 = load_row(hidden, cell, ctarg, outp, decay, __shfl(r, 0, 64), lane);
        RowT b1 = load_row(hidden, cell, ctarg, outp, decay, __shfl(r, 1, 64), lane);

        while (true) {
            const int   rs2 = __shfl(r, 2, 64), rs3 = __shfl(r, 3, 64),
                        rs4 = __shfl(r, 4, 64), rs5 = __shfl(r, 5, 64),
                        rs6 = __shfl(r, 6, 64), rs7 = __shfl(r, 7, 64);
            const float ss2 = __shfl(st, 2, 64), ss3 = __shfl(st, 3, 64),
                        ss4 = __shfl(st, 4, 64), ss5 = __shfl(st, 5, 64),
                        ss6 = __shfl(st, 6, 64), ss7 = __shfl(st, 7, 64);

            // ---- staging: 3-deep rotation (b0,b1 pre-loaded last iter) ----
            RowT b2 = load_row(hidden, cell, ctarg, outp, decay, rs2, lane);
            STrow<0>(Aw, b0, ss0, lane); b0 = load_row(hidden, cell, ctarg, outp, decay, rs3, lane);
            STrow<1>(Aw, b1, ss1, lane); b1 = load_row(hidden, cell, ctarg, outp, decay, rs4, lane);
            STrow<2>(Aw, b2, ss2, lane); b2 = load_row(hidden, cell, ctarg, outp, decay, rs5, lane);
            STrow<3>(Aw, b0, ss3, lane); b0 = load_row(hidden, cell, ctarg, outp, decay, rs6, lane);
            STrow<4>(Aw, b1, ss4, lane); b1 = load_row(hidden, cell, ctarg, outp, decay, rs7, lane);
            STrow<5>(Aw, b2, ss5, lane);
            STrow<6>(Aw, b0, ss6, lane);
            STrow<7>(Aw, b1, ss7, lane);

            // ---- cross-tile prefetch: next metadata + first 2 rows ----
            const int  next    = tile + stride;
            const bool hasNext = next < ntiles;        // wave-uniform
            int nr = 0, ne = 0, nvalid = 0; float nst = 0.f, ncoef = 0.f;
            float nss0 = 0.f, nss1 = 0.f;
            if (hasNext) {
                META(next, nr, nst, ne, ncoef, nvalid);
                nss0 = __shfl(nst, 0, 64);
                nss1 = __shfl(nst, 1, 64);
                b0 = load_row(hidden, cell, ctarg, outp, decay, __shfl(nr, 0, 64), lane);
                b1 = load_row(hidden, cell, ctarg, outp, decay, __shfl(nr, 1, 64), lane);
            }

            // ---- MFMA: C[16][32] (rows 0-7 = v, 8-15 = h) ----
            f32x4 C0 = {0.f,0.f,0.f,0.f}, C1 = {0.f,0.f,0.f,0.f};
            const int abase = m * 512 + 16 * g;
            const int swza  = (m & 7) << 4;
#pragma unroll
            for (int c = 0; c < 8; ++c) {
                const short8 a  = *(const short8*)(Aw  + ((abase + 64 * c) ^ swza));
                const short8 w0 = *(const short8*)(WTs + ((abase + 64 * c) ^ swza));
                const short8 w1 = *(const short8*)(WTs + ((abase + 8192 + 64 * c) ^ swza));
                C0 = __builtin_amdgcn_mfma_f32_16x16x32_bf16(a, w0, C0, 0, 0, 0);
                C1 = __builtin_amdgcn_mfma_f32_16x16x32_bf16(a, w1, C1, 0, 0, 0);
            }

            // ---- term 2: C rows 0-7 (g<2), row = 4g+reg, col = m ----
            float sp[4];
#pragma unroll
            for (int reg = 0; reg < 4; ++reg)
                sp[reg] = softplus_f(C0[reg] + b_lo) + softplus_f(C1[reg] + b_hi);
#pragma unroll
            for (int mk = 1; mk <= 8; mk <<= 1) {
#pragma unroll
                for (int reg = 0; reg < 4; ++reg) sp[reg] += __shfl_xor(sp[reg], mk, 64);
            }
            float t2 = 0.f;
#pragma unroll
            for (int reg = 0; reg < 4; ++reg) {
                const float cf = __shfl(coef, 4 * g + reg, 64);  // coef of row 4g+reg
                t2 += cf * sp[reg];
            }
            if (m == 0 && g < 2) acc += t2;

            // ---- term 1: C rows 8-15 (g=2,3) gathered at column e ----
            float kv = 0.f, kb = 0.f;
#pragma unroll
            for (int rr = 0; rr < 8; ++rr) {
                const int   er   = __shfl(e, rr, 64);            // e of flat row rr
                const float cand = (er < 16) ? C0[rr & 3] : C1[rr & 3];
                const float val  = __shfl(cand, 32 + ((rr >> 2) << 4) + (er & 15), 64);
                const float be   = bias_s[er];
                if (lane == rr) { kv = val; kb = be; }
            }
            if (lane < 8 && valid)
                acc -= __logf(softplus_f(kv + kb));

            if (!hasNext) break;
            r = nr; st = nst; e = ne; coef = ncoef; valid = nvalid;
            ss0 = nss0; ss1 = nss1;
            tile = next;
        }
    }
#undef META

    // wave reduce + block reduce
#pragma unroll
    for (int mk = 1; mk < 64; mk <<= 1) acc += __shfl_xor(acc, mk, 64);
    if (lane == 0) wacc[q] = acc;
    __syncthreads();
    if (tid == 0) partial[blockIdx.x] = wacc[0] + wacc[1] + wacc[2] + wacc[3];
}

// Output: single float32 scalar.
__global__ __launch_bounds__(256) void nhll_finalize(
    const float* __restrict__ partial, float* __restrict__ out)
{
    __shared__ float red[4];
    float s = 0.f;
    for (int i = threadIdx.x; i < NB; i += 256) s += partial[i];
    for (int mk = 1; mk < 64; mk <<= 1) s += __shfl_xor(s, mk, 64);
    if ((threadIdx.x & 63) == 0) red[threadIdx.x >> 6] = s;
    __syncthreads();
    if (threadIdx.x == 0)
        out[0] = red[0] + red[1] + red[2] + red[3];
}

extern "C" void kernel_launch(void* const* d_in, const int* in_sizes, int n_in,
                              void* d_out, int out_size, void* d_ws, size_t ws_size,
                              hipStream_t stream) {
    const int*   events = (const int*)  d_in[0];   // event_seqs  [B,L] int32
    const int*   lens   = (const int*)  d_in[1];   // seqs_length [B]   int32
    const float* ttime  = (const float*)d_in[2];   // total_time  [B]
    const float* hidden = (const float*)d_in[3];   // [L,B,H]
    const float* cell   = (const float*)d_in[4];   // [L,B,H]
    const float* ctarg  = (const float*)d_in[5];   // [L,B,H]
    const float* outp   = (const float*)d_in[6];   // [L,B,H]
    const float* decay  = (const float*)d_in[7];   // [L,B,H]
    const float* simt   = (const float*)d_in[8];   // [L,B]
    const float* W      = (const float*)d_in[9];   // [H,K]
    const float* bias   = (const float*)d_in[10];  // [K]

    float* part = (float*)d_ws;                    // NB floats
    float* out  = (float*)d_out;

    nhll_main<<<NB, 256, 0, stream>>>(events, lens, ttime, hidden, cell, ctarg,
                                      outp, decay, simt, W, bias, part);
    nhll_finalize<<<1, 256, 0, stream>>>(part, out);
}